// Round 1
// 553.088 us; speedup vs baseline: 1.0056x; 1.0056x over previous
//
#include <hip/hip_runtime.h>

// ---------- types ----------
typedef __attribute__((ext_vector_type(8))) short short8;   // 8 bf16 (4 VGPRs)
typedef __attribute__((ext_vector_type(4))) float f32x4;

// ---------- problem constants ----------
#define NB     32
#define NC     128          // Cin == Cout == 128
#define HW     112
#define PLANE  12544        // 112*112
#define XTOT   51380224     // 32*128*112*112
#define NGX    1427229      // ceil(XTOT/36)
#define PADW   114
#define PADPLANE 12996      // 114*114
// workspace layout (bytes)
#define XPAD_BYTES 106463232ULL   // 32*114*114*128 * 2
#define WG_OFF     XPAD_BYTES
#define SE_OFF     (XPAD_BYTES + 294912ULL)

__device__ __forceinline__ void gld_lds16(const void* g, void* l) {
  __builtin_amdgcn_global_load_lds(
      (__attribute__((address_space(1))) unsigned int*)g,
      (__attribute__((address_space(3))) unsigned int*)l, 16, 0, 0);
}

__device__ __forceinline__ float qmax4(float4 v, float m) {
  m = fmaxf(m, fabsf(v.x)); m = fmaxf(m, fabsf(v.y));
  m = fmaxf(m, fabsf(v.z)); m = fmaxf(m, fabsf(v.w));
  return m;
}

// exponent e = floor(log2(m)) for normal m>0 (exact, unlike log2f+floorf)
__device__ __forceinline__ int bfp_exp(float m) {
  int e = 0;
  if (m > 0.f) {
    e = (int)((__float_as_uint(m) >> 23) & 255) - 127;
    if (e < -100) e = -100;  // guard denormal groups (cannot occur for N(0,1) data)
  }
  return e;
}

// q = clip(rint(v * 2^(7-e)), -128, 127) * 2^(e-7); exactly bf16-representable
__device__ __forceinline__ unsigned short bfp_q(float v, float inv, float st) {
  float qq = fminf(fmaxf(rintf(v * inv), -128.f), 127.f) * st;
  return (unsigned short)(__float_as_uint(qq) >> 16);  // exact truncation
}

// ---------- kernel 1: per-group exponent of x (LDS-coalesced) ----------
// block handles 256 groups = 9216 floats = 36864 B, loaded block-contiguous.
__global__ __launch_bounds__(256) void quant_step_x(const float* __restrict__ x,
                                                    signed char* __restrict__ se) {
  __shared__ float lds[9216];
  const int t = threadIdx.x;
  const int base = blockIdx.x * 9216;              // < 2^26, int ok
  const float4* src = (const float4*)(x + base);
  const int rem4 = (XTOT - base) >> 2;             // # valid float4 slots from base
#pragma unroll
  for (int j = 0; j < 9; ++j) {
    int idx = j * 256 + t;
    float4 v = make_float4(0.f, 0.f, 0.f, 0.f);
    if (idx < rem4) v = src[idx];                  // XTOT % 4 == 0: no sub-vec tail
    ((float4*)lds)[idx] = v;
  }
  __syncthreads();
  int g = blockIdx.x * 256 + t;
  if (g >= NGX) return;
  const float4* p4 = (const float4*)(lds + t * 36);  // 144 B -> 16B aligned
  float m = 0.f;
#pragma unroll
  for (int j = 0; j < 9; ++j) m = qmax4(p4[j], m);
  se[g] = (signed char)bfp_exp(m);
}

// ---------- kernel 2: quantize + reorder weights to [step=rs*4+cib][co][ci32] bf16 ----------
__global__ __launch_bounds__(64) void quant_w_kernel(const float* __restrict__ w,
                                                     unsigned short* __restrict__ wg) {
  int g = blockIdx.x * 64 + threadIdx.x;   // 4096 groups, exact
  if (g >= 4096) return;
  const float4* p4 = (const float4*)(w + g * 36);
  float4 v[9];
  float m = 0.f;
#pragma unroll
  for (int j = 0; j < 9; ++j) { v[j] = p4[j]; m = qmax4(v[j], m); }
  int e = bfp_exp(m);
  float inv = __uint_as_float((unsigned)(134 - e) << 23);  // 2^(7-e)
  float st  = __uint_as_float((unsigned)(120 + e) << 23);  // 2^(e-7)
#pragma unroll
  for (int j = 0; j < 9; ++j) {
    float tmp[4] = {v[j].x, v[j].y, v[j].z, v[j].w};
#pragma unroll
    for (int k = 0; k < 4; ++k) {
      int i = j * 4 + k;
      int f = g * 36 + i;           // flat index in [co][ci][kh][kw]
      int co = f / 1152;
      int rem = f % 1152;
      int ci = rem / 9;
      int rs = rem % 9;             // kh*3+kw
      int stp = rs * 4 + (ci >> 5);
      wg[(stp * 128 + co) * 32 + (ci & 31)] = bfp_q(tmp[k], inv, st);
    }
  }
}

// ---------- kernel 3: quantize x + transpose NCHW -> padded NHWC bf16 (+ fused halo zero) ----------
#define TSTR 136   // tile row stride in ushorts (272 B: 16B-aligned, breaks 8-way bank conflict)
__global__ __launch_bounds__(256) void quant_pad_x(const float* __restrict__ x,
                                                   const signed char* __restrict__ se,
                                                   unsigned short* __restrict__ xpad) {
  __shared__ unsigned short tile[32 * TSTR];   // [p_local][ci] padded
  int b = blockIdx.y;
  int p0 = blockIdx.x * 32;
  int t = threadIdx.x;

  // fused halo zeroing (replaces the old border_zero kernel): first 904 blocks
  int hid = (blockIdx.y * 392 + blockIdx.x) * 256 + t;
  if (hid < NB * 452 * 16) {
    int hb = hid / (452 * 16);
    int r = hid % (452 * 16);
    int pos = r >> 4, cc = r & 15;
    int hp, wp;
    if (pos < 114)      { hp = 0;             wp = pos; }
    else if (pos < 228) { hp = 113;           wp = pos - 114; }
    else if (pos < 340) { hp = pos - 228 + 1; wp = 0; }
    else                { hp = pos - 340 + 1; wp = 113; }
    float4 z = make_float4(0.f, 0.f, 0.f, 0.f);
    *(float4*)&xpad[((size_t)((hb * 114 + hp) * 114 + wp)) * 128 + cc * 8] = z;
  }

  int pq  = (t & 7) * 4;        // p offset 0..28
  int ci0 = (t >> 3) * 4;       // 0..124
  unsigned short q[4][4];
#pragma unroll
  for (int i = 0; i < 4; ++i) {
    int ci = ci0 + i;
    int f = (b * 128 + ci) * PLANE + p0 + pq;
    float4 v = *(const float4*)(x + f);
    float vv[4] = {v.x, v.y, v.z, v.w};
#pragma unroll
    for (int j = 0; j < 4; ++j) {
      int e = se[(f + j) / 36];
      float inv = __uint_as_float((unsigned)(134 - e) << 23);
      float st  = __uint_as_float((unsigned)(120 + e) << 23);
      q[i][j] = bfp_q(vv[j], inv, st);
    }
  }
#pragma unroll
  for (int j = 0; j < 4; ++j)
    *(ushort4*)&tile[(pq + j) * TSTR + ci0] = make_ushort4(q[0][j], q[1][j], q[2][j], q[3][j]);
  __syncthreads();
  int pl = t >> 3;              // 0..31
  int cc = t & 7;               // ci chunk of 16
  int p = p0 + pl;
  int h = p / 112, w = p % 112;
  float4 v0 = *(const float4*)&tile[pl * TSTR + cc * 16];
  float4 v1 = *(const float4*)&tile[pl * TSTR + cc * 16 + 8];
  size_t dst = ((size_t)((b * 114 + h + 1) * 114 + (w + 1))) * 128 + cc * 16;
  *(float4*)&xpad[dst]     = v0;
  *(float4*)&xpad[dst + 8] = v1;
}

// ---------- kernel 4: implicit-GEMM conv, bf16 MFMA, 2-phase double-buffered pipeline ----------
// block = 256 (4 waves, 2x2), tile = 128 co x 128 p, K = 36 steps of (kh,kw,ci32).
// T3-minimum schedule: issue next step's global_load_lds BEFORE current ds_read+MFMA;
// ONE syncthreads (vmcnt(0)+barrier) per step. Buffers at compile-time LDS offsets.
__global__ __launch_bounds__(256) void conv_mfma(const unsigned short* __restrict__ xpad,
                                                 const unsigned short* __restrict__ wg,
                                                 const float* __restrict__ bias,
                                                 float* __restrict__ out) {
  __shared__ unsigned short smem[16384];   // 32 KB: buf0 [0,16K): A 8K + B 8K; buf1 [16K,32K)
  char* smb = (char*)smem;
  const int t = threadIdx.x;
  const int lane = t & 63, wv = t >> 6;
  const int lane15 = lane & 15, quad = lane >> 4;
  const int wm = wv >> 1, wn = wv & 1;
  const int b = blockIdx.y;
  const int p0 = blockIdx.x * 128;

  // staging sources; chunk position XOR-swizzled (baked into source addr so
  // global_load_lds's lane-contiguous LDS dest still works; breaks bank conflicts)
  int a_src[2], b_src[2];
#pragma unroll
  for (int i = 0; i < 2; ++i) {
    int idx = t + i * 256;
    int row = idx >> 2;          // co (A) / p_local (B)
    int c = idx & 3;             // physical 16B chunk slot
    int sw = (row >> 1) & 3;
    a_src[i] = row * 32 + (c ^ sw) * 8;                    // elems into wg step-block
    int p = p0 + row;
    int h = p / 112, ww = p % 112;
    b_src[i] = ((b * 114 + h) * 114 + ww) * 128 + (c ^ sw) * 8;  // + (r*114+s)*128 + cib*32
  }

  // fragment LDS byte offsets relative to buffer base (constant across K steps)
  int a_off[4], b_off[4];
#pragma unroll
  for (int f = 0; f < 4; ++f) {
    int row = wm * 64 + f * 16 + lane15;
    a_off[f] = row * 64 + ((quad ^ ((row >> 1) & 3)) * 16);
    int prow = wn * 64 + f * 16 + lane15;
    b_off[f] = 8192 + prow * 64 + ((quad ^ ((prow >> 1) & 3)) * 16);
  }

  f32x4 acc[4][4];
  f32x4 zero = {0.f, 0.f, 0.f, 0.f};
#pragma unroll
  for (int i = 0; i < 4; ++i)
#pragma unroll
    for (int j = 0; j < 4; ++j) acc[i][j] = zero;

  auto stage = [&](int step, char* dst) {
    int rs = step >> 2, cib = step & 3;
    int r = (rs * 11) >> 5;                       // rs/3 for rs in [0,9)
    int s = rs - r * 3;
    int aofs = step * 4096;                       // 128*32 elems per step-block
    int bofs = (r * 114 + s) * 128 + cib * 32;    // shifted padded-NHWC offset
#pragma unroll
    for (int i = 0; i < 2; ++i) {
      gld_lds16(wg + aofs + a_src[i],   dst + wv * 1024 + i * 4096);
      gld_lds16(xpad + b_src[i] + bofs, dst + 8192 + wv * 1024 + i * 4096);
    }
  };

  auto compute = [&](const char* sb) {
    short8 af[4], bf[4];
#pragma unroll
    for (int f = 0; f < 4; ++f) af[f] = *(const short8*)(sb + a_off[f]);
#pragma unroll
    for (int f = 0; f < 4; ++f) bf[f] = *(const short8*)(sb + b_off[f]);
#pragma unroll
    for (int i = 0; i < 4; ++i)
#pragma unroll
      for (int j = 0; j < 4; ++j)
        acc[i][j] = __builtin_amdgcn_mfma_f32_16x16x32_bf16(af[i], bf[j], acc[i][j], 0, 0, 0);
  };

  char* B0 = smb;            // even steps
  char* B1 = smb + 16384;    // odd steps

  stage(0, B0);
  __syncthreads();                       // prologue drain
  for (int it = 0; it < 18; ++it) {
    stage(2 * it + 1, B1);               // prefetch odd step (hidden under compute)
    compute(B0);                         // ds_read + 16 MFMA on even step
    __syncthreads();                     // vmcnt(0): B1 ready; B0 reads done
    if (it < 17) stage(2 * it + 2, B0);  // prefetch next even step
    compute(B1);
    __syncthreads();
  }

  // epilogue: C/D layout col=lane&15 (p), row=quad*4+reg (co); + bias
#pragma unroll
  for (int i = 0; i < 4; ++i)
#pragma unroll
    for (int j = 0; j < 4; ++j) {
      int p = p0 + wn * 64 + j * 16 + lane15;
#pragma unroll
      for (int rr = 0; rr < 4; ++rr) {
        int co = wm * 64 + i * 16 + quad * 4 + rr;
        out[(b * 128 + co) * PLANE + p] = acc[i][j][rr] + bias[co];
      }
    }
}

extern "C" void kernel_launch(void* const* d_in, const int* in_sizes, int n_in,
                              void* d_out, int out_size, void* d_ws, size_t ws_size,
                              hipStream_t stream) {
  const float* x    = (const float*)d_in[0];
  const float* w    = (const float*)d_in[1];
  const float* bias = (const float*)d_in[2];
  float* out = (float*)d_out;
  char* ws = (char*)d_ws;
  unsigned short* xpad = (unsigned short*)ws;
  unsigned short* wg   = (unsigned short*)(ws + WG_OFF);
  signed char*    se   = (signed char*)(ws + SE_OFF);

  quant_step_x<<<(NGX + 255) / 256, 256, 0, stream>>>(x, se);
  quant_w_kernel<<<64, 64, 0, stream>>>(w, wg);
  quant_pad_x<<<dim3(392, 32), 256, 0, stream>>>(x, se, xpad);
  conv_mfma<<<dim3(98, 32), 256, 0, stream>>>(xpad, wg, bias, out);
}

// Round 2
// 517.651 us; speedup vs baseline: 1.0745x; 1.0685x over previous
//
#include <hip/hip_runtime.h>

// ---------- types ----------
typedef __attribute__((ext_vector_type(8))) short short8;   // 8 bf16 (4 VGPRs)
typedef __attribute__((ext_vector_type(4))) float f32x4;

// ---------- problem constants ----------
#define NB     32
#define NC     128          // Cin == Cout == 128
#define HW     112
#define PLANE  12544        // 112*112
#define XTOT   51380224     // 32*128*112*112
#define NGX    1427229      // ceil(XTOT/36)
#define PADW   114
#define PADPLANE 12996      // 114*114
// workspace layout (bytes)
#define XPAD_BYTES 106463232ULL   // 32*114*114*128 * 2
#define WG_OFF     XPAD_BYTES
#define SE_OFF     (XPAD_BYTES + 294912ULL)

__device__ __forceinline__ void gld_lds16(const void* g, void* l) {
  __builtin_amdgcn_global_load_lds(
      (__attribute__((address_space(1))) unsigned int*)g,
      (__attribute__((address_space(3))) unsigned int*)l, 16, 0, 0);
}

__device__ __forceinline__ float qmax4(float4 v, float m) {
  m = fmaxf(m, fabsf(v.x)); m = fmaxf(m, fabsf(v.y));
  m = fmaxf(m, fabsf(v.z)); m = fmaxf(m, fabsf(v.w));
  return m;
}

// exponent e = floor(log2(m)) for normal m>0 (exact, unlike log2f+floorf)
__device__ __forceinline__ int bfp_exp(float m) {
  int e = 0;
  if (m > 0.f) {
    e = (int)((__float_as_uint(m) >> 23) & 255) - 127;
    if (e < -100) e = -100;  // guard denormal groups (cannot occur for N(0,1) data)
  }
  return e;
}

// q = clip(rint(v * 2^(7-e)), -128, 127) * 2^(e-7); exactly bf16-representable
__device__ __forceinline__ unsigned short bfp_q(float v, float inv, float st) {
  float qq = fminf(fmaxf(rintf(v * inv), -128.f), 127.f) * st;
  return (unsigned short)(__float_as_uint(qq) >> 16);  // exact truncation
}

__device__ __forceinline__ float mk_inv(int e) {
  return __uint_as_float((unsigned)(134 - e) << 23);   // 2^(7-e)
}
__device__ __forceinline__ float mk_st(int e) {
  return __uint_as_float((unsigned)(120 + e) << 23);   // 2^(e-7)
}

// ---------- kernel 1: per-group exponent of x (LDS-coalesced) ----------
__global__ __launch_bounds__(256) void quant_step_x(const float* __restrict__ x,
                                                    signed char* __restrict__ se) {
  __shared__ float lds[9216];
  const int t = threadIdx.x;
  const int base = blockIdx.x * 9216;
  const float4* src = (const float4*)(x + base);
  const int rem4 = (XTOT - base) >> 2;
#pragma unroll
  for (int j = 0; j < 9; ++j) {
    int idx = j * 256 + t;
    float4 v = make_float4(0.f, 0.f, 0.f, 0.f);
    if (idx < rem4) v = src[idx];
    ((float4*)lds)[idx] = v;
  }
  __syncthreads();
  int g = blockIdx.x * 256 + t;
  if (g >= NGX) return;
  const float4* p4 = (const float4*)(lds + t * 36);
  float m = 0.f;
#pragma unroll
  for (int j = 0; j < 9; ++j) m = qmax4(p4[j], m);
  se[g] = (signed char)bfp_exp(m);
}

// ---------- kernel 2: quantize + reorder weights, LDS-staged, coalesced out ----------
// 16 blocks x 256 threads; block owns co in [8b, 8b+8) = 9216 floats = 256 groups exactly.
__global__ __launch_bounds__(256) void quant_w_kernel(const float* __restrict__ w,
                                                      unsigned short* __restrict__ wg) {
  __shared__ float wl[9216];
  __shared__ float wi[256], wsr[256];
  const int blk = blockIdx.x;
  const int t = threadIdx.x;
  const int base = blk * 9216;
  const float4* src = (const float4*)(w + base);
#pragma unroll
  for (int j = 0; j < 9; ++j) ((float4*)wl)[j * 256 + t] = src[j * 256 + t];
  __syncthreads();
  {
    const float4* p4 = (const float4*)(wl + t * 36);
    float m = 0.f;
#pragma unroll
    for (int j = 0; j < 9; ++j) m = qmax4(p4[j], m);
    int e = bfp_exp(m);
    wi[t] = mk_inv(e); wsr[t] = mk_st(e);
  }
  __syncthreads();
  const int cloc = t >> 5, cil = t & 31;
  const int co = blk * 8 + cloc;
#pragma unroll
  for (int stp = 0; stp < 36; ++stp) {
    int cib = stp & 3, rs = stp >> 2;
    int ci = cib * 32 + cil;
    int fl = cloc * 1152 + ci * 9 + rs;   // local index in wl (< 9216)
    int g = fl / 36;                      // local group
    wg[(stp * 128 + co) * 32 + cil] = bfp_q(wl[fl], wi[g], wsr[g]);
  }
}

// ---------- kernel 3: quantize x + transpose NCHW -> padded NHWC bf16 (+ fused halo zero) ----------
#define TSTR 136   // tile row stride in ushorts
__global__ __launch_bounds__(256) void quant_pad_x(const float* __restrict__ x,
                                                   const signed char* __restrict__ se,
                                                   unsigned short* __restrict__ xpad) {
  __shared__ unsigned short tile[32 * TSTR];
  __shared__ float4 ist4[128];          // (inv0, st0, inv1, st1) per ci
  __shared__ unsigned char roll[128];   // rollover offset within [1,36]
  int b = blockIdx.y;
  int p0 = blockIdx.x * 32;
  int t = threadIdx.x;

  // fused halo zeroing: first 904 (block,thread) slots
  int hid = (blockIdx.y * 392 + blockIdx.x) * 256 + t;
  if (hid < NB * 452 * 16) {
    int hb = hid / (452 * 16);
    int r = hid % (452 * 16);
    int pos = r >> 4, cc = r & 15;
    int hp, wp;
    if (pos < 114)      { hp = 0;             wp = pos; }
    else if (pos < 228) { hp = 113;           wp = pos - 114; }
    else if (pos < 340) { hp = pos - 228 + 1; wp = 0; }
    else                { hp = pos - 340 + 1; wp = 113; }
    float4 z = make_float4(0.f, 0.f, 0.f, 0.f);
    *(float4*)&xpad[((size_t)((hb * 114 + hp) * 114 + wp)) * 128 + cc * 8] = z;
  }

  // per-ci group-exp prefetch: a 32-wide p window spans at most 2 groups
  if (t < 128) {
    int ci = t;
    int f0 = (b * 128 + ci) * PLANE + p0;
    int g = f0 / 36;
    int rem = f0 - g * 36;
    roll[ci] = (unsigned char)(36 - rem);
    int g1 = g + 1; if (g1 > NGX - 1) g1 = NGX - 1;
    int e0 = se[g], e1 = se[g1];
    ist4[ci] = make_float4(mk_inv(e0), mk_st(e0), mk_inv(e1), mk_st(e1));
  }
  __syncthreads();

  int pq  = (t & 7) * 4;        // p offset 0..28
  int ci0 = (t >> 3) * 4;       // 0..124
  unsigned short q[4][4];
#pragma unroll
  for (int i = 0; i < 4; ++i) {
    int ci = ci0 + i;
    int f = (b * 128 + ci) * PLANE + p0 + pq;
    float4 v = *(const float4*)(x + f);
    float vv[4] = {v.x, v.y, v.z, v.w};
    float4 is_ = ist4[ci];
    int rl = roll[ci];
#pragma unroll
    for (int j = 0; j < 4; ++j) {
      bool sec = (pq + j) >= rl;
      float inv = sec ? is_.z : is_.x;
      float st  = sec ? is_.w : is_.y;
      q[i][j] = bfp_q(vv[j], inv, st);
    }
  }
#pragma unroll
  for (int j = 0; j < 4; ++j)
    *(ushort4*)&tile[(pq + j) * TSTR + ci0] = make_ushort4(q[0][j], q[1][j], q[2][j], q[3][j]);
  __syncthreads();
  int pl = t >> 3;              // 0..31
  int cc = t & 7;               // ci chunk of 16
  int p = p0 + pl;
  int h = p / 112, w = p % 112;
  float4 v0 = *(const float4*)&tile[pl * TSTR + cc * 16];
  float4 v1 = *(const float4*)&tile[pl * TSTR + cc * 16 + 8];
  size_t dst = ((size_t)((b * 114 + h + 1) * 114 + (w + 1))) * 128 + cc * 16;
  *(float4*)&xpad[dst]     = v0;
  *(float4*)&xpad[dst + 8] = v1;
}

// ---------- kernel 4: implicit-GEMM conv, bf16 MFMA ----------
// 3-buffer, 2-step-lookahead pipeline with counted vmcnt (T3+T4): loads stay in
// flight across barriers; one "s_waitcnt vmcnt(4); s_barrier" per K-step.
#define BUFSZ 16384
#define WB4() asm volatile("s_waitcnt vmcnt(4)\n\ts_barrier" ::: "memory")
#define WB0() asm volatile("s_waitcnt vmcnt(0)\n\ts_barrier" ::: "memory")

__global__ __launch_bounds__(256) void conv_mfma(const unsigned short* __restrict__ xpad,
                                                 const unsigned short* __restrict__ wg,
                                                 const float* __restrict__ bias,
                                                 float* __restrict__ out) {
  __shared__ __align__(16) char smb[3 * BUFSZ];   // 48 KB -> 3 blocks/CU
  const int t = threadIdx.x;
  const int lane = t & 63, wv = t >> 6;
  const int lane15 = lane & 15, quad = lane >> 4;
  const int wm = wv >> 1, wn = wv & 1;
  const int b = blockIdx.y;
  const int p0 = blockIdx.x * 128;

  // staging sources; chunk position XOR-swizzled (baked into source addr so
  // global_load_lds's lane-contiguous LDS dest still works)
  int a_src[2], b_src[2];
#pragma unroll
  for (int i = 0; i < 2; ++i) {
    int idx = t + i * 256;
    int row = idx >> 2;          // co (A) / p_local (B)
    int c = idx & 3;             // physical 16B chunk slot
    int sw = (row >> 1) & 3;
    a_src[i] = row * 32 + (c ^ sw) * 8;
    int p = p0 + row;
    int h = p / 112, ww = p % 112;
    b_src[i] = ((b * 114 + h) * 114 + ww) * 128 + (c ^ sw) * 8;
  }

  // fragment LDS byte offsets relative to buffer base
  int a_off[4], b_off[4];
#pragma unroll
  for (int f = 0; f < 4; ++f) {
    int row = wm * 64 + f * 16 + lane15;
    a_off[f] = row * 64 + ((quad ^ ((row >> 1) & 3)) * 16);
    int prow = wn * 64 + f * 16 + lane15;
    b_off[f] = 8192 + prow * 64 + ((quad ^ ((prow >> 1) & 3)) * 16);
  }

  f32x4 acc[4][4];
  f32x4 zero = {0.f, 0.f, 0.f, 0.f};
#pragma unroll
  for (int i = 0; i < 4; ++i)
#pragma unroll
    for (int j = 0; j < 4; ++j) acc[i][j] = zero;

  auto stage = [&](int step, char* dst) {
    int rs = step >> 2, cib = step & 3;
    int r = (rs * 11) >> 5;                       // rs/3 for rs in [0,9)
    int s = rs - r * 3;
    int aofs = step * 4096;
    int bofs = (r * 114 + s) * 128 + cib * 32;
#pragma unroll
    for (int i = 0; i < 2; ++i) {
      gld_lds16(wg + aofs + a_src[i],   dst + wv * 1024 + i * 4096);
      gld_lds16(xpad + b_src[i] + bofs, dst + 8192 + wv * 1024 + i * 4096);
    }
  };

  auto compute = [&](const char* sb) {
    short8 af[4], bf[4];
#pragma unroll
    for (int f = 0; f < 4; ++f) af[f] = *(const short8*)(sb + a_off[f]);
#pragma unroll
    for (int f = 0; f < 4; ++f) bf[f] = *(const short8*)(sb + b_off[f]);
    __builtin_amdgcn_s_setprio(1);
#pragma unroll
    for (int i = 0; i < 4; ++i)
#pragma unroll
      for (int j = 0; j < 4; ++j)
        acc[i][j] = __builtin_amdgcn_mfma_f32_16x16x32_bf16(af[i], bf[j], acc[i][j], 0, 0, 0);
    __builtin_amdgcn_s_setprio(0);
  };

  char* B0 = smb;
  char* B1 = smb + BUFSZ;
  char* B2 = smb + 2 * BUFSZ;

  stage(0, B0);
  stage(1, B1);
#pragma unroll 1
  for (int tt = 0; tt < 33; tt += 3) {
    WB4(); stage(tt + 2, B2); compute(B0);
    WB4(); stage(tt + 3, B0); compute(B1);
    WB4(); stage(tt + 4, B1); compute(B2);
  }
  // tail: steps 33 (B0), 34 (B1), 35 (B2)
  WB4(); stage(35, B2); compute(B0);
  WB4(); compute(B1);
  WB0(); compute(B2);

  // epilogue: C/D layout col=lane&15 (p), row=quad*4+reg (co); + bias
#pragma unroll
  for (int i = 0; i < 4; ++i)
#pragma unroll
    for (int j = 0; j < 4; ++j) {
      int p = p0 + wn * 64 + j * 16 + lane15;
#pragma unroll
      for (int rr = 0; rr < 4; ++rr) {
        int co = wm * 64 + i * 16 + quad * 4 + rr;
        out[(b * 128 + co) * PLANE + p] = acc[i][j][rr] + bias[co];
      }
    }
}

extern "C" void kernel_launch(void* const* d_in, const int* in_sizes, int n_in,
                              void* d_out, int out_size, void* d_ws, size_t ws_size,
                              hipStream_t stream) {
  const float* x    = (const float*)d_in[0];
  const float* w    = (const float*)d_in[1];
  const float* bias = (const float*)d_in[2];
  float* out = (float*)d_out;
  char* ws = (char*)d_ws;
  unsigned short* xpad = (unsigned short*)ws;
  unsigned short* wg   = (unsigned short*)(ws + WG_OFF);
  signed char*    se   = (signed char*)(ws + SE_OFF);

  quant_step_x<<<(NGX + 255) / 256, 256, 0, stream>>>(x, se);
  quant_w_kernel<<<16, 256, 0, stream>>>(w, wg);
  quant_pad_x<<<dim3(392, 32), 256, 0, stream>>>(x, se, xpad);
  conv_mfma<<<dim3(98, 32), 256, 0, stream>>>(xpad, wg, bias, out);
}